// Round 10
// baseline (363.683 us; speedup 1.0000x reference)
//
#include <hip/hip_runtime.h>

#define CROP_H 14
#define CROP_W 14
#define IMG_H 200
#define IMG_W 200
#define IMG_C 256
#define N_IMG 8
#define N_BOXES 1000
#define PLANE (IMG_H * IMG_W)
#define HW (CROP_H * CROP_W)             // 196
#define NPAIR (N_BOXES / 2)              // 500
#define CHUNKS 49                        // 12544 / 256

typedef float f2 __attribute__((ext_vector_type(2)));

// ---- Kernel A: bin boxes by n; precompute per-(box,t) coord tables.
__global__ __launch_bounds__(512) void prep_kernel(
    const float* __restrict__ boxes, const int* __restrict__ box_idx,
    int* __restrict__ order, float* __restrict__ ytab, float* __restrict__ xtab)
{
    __shared__ int counts[N_IMG];
    __shared__ int offsets[N_IMG];
    int tid  = threadIdx.x;
    int wave = tid >> 6;
    int lane = tid & 63;

    int cnt = 0;
    for (int i = lane; i < N_BOXES; i += 64) cnt += (box_idx[i] == wave) ? 1 : 0;
    for (int off = 32; off; off >>= 1) cnt += __shfl_down(cnt, off);
    if (lane == 0) counts[wave] = cnt;
    __syncthreads();
    if (tid == 0) {
        int s = 0;
        for (int i = 0; i < N_IMG; i++) { offsets[i] = s; s += counts[i]; }
    }
    __syncthreads();

    int base = offsets[wave];
    for (int i0 = 0; i0 < N_BOXES; i0 += 64) {
        int i = i0 + lane;
        bool p = (i < N_BOXES) && (box_idx[i] == wave);
        unsigned long long m = __ballot(p);
        unsigned long long below = m & ((1ull << lane) - 1ull);
        if (p) order[base + __popcll(below)] = i;
        base += __popcll(m);
    }

    // Raw coordinates (reference arithmetic order exactly; IEEE divide).
    for (int i = tid; i < N_BOXES * CROP_H; i += 512) {
        int b = i / CROP_H;
        int t = i % CROP_H;
        float y1 = boxes[b * 4 + 0];
        float x1 = boxes[b * 4 + 1];
        float y2 = boxes[b * 4 + 2];
        float x2 = boxes[b * 4 + 3];
        float h_scale = (y2 - y1) * (float)(IMG_H - 1) / (float)(CROP_H - 1);
        float w_scale = (x2 - x1) * (float)(IMG_W - 1) / (float)(CROP_W - 1);
        ytab[i] = y1 * (float)(IMG_H - 1) + (float)t * h_scale;
        xtab[i] = x1 * (float)(IMG_W - 1) + (float)t * w_scale;
    }
}

// ---- Kernel B: direct bilinear; horizontal tap pairs as ONE dwordx2 each
// (2 memory instructions per output instead of 4). Blocks = 256 fully-active
// threads over (box-pair, 32 channels of class r, 196 xy); blockIdx&7 = r,
// so each (n,c) plane is fetched by exactly one XCD's L2 (R7's 157 MB fetch)
// while keeping R4's wave count. Box-pair-minor order = n-grouped L2 sweep.
__global__ __launch_bounds__(256) void crop_resize_kernel(
    const float* __restrict__ image,   // (8,256,200,200)
    const int*   __restrict__ box_idx, // (1000,)
    const int*   __restrict__ order,   // (1000,) n-grouped
    const float* __restrict__ ytab,    // (1000,14) raw in_y
    const float* __restrict__ xtab,    // (1000,14) raw in_x
    float*       __restrict__ out)     // (1000,256,14,14)
{
    int r = blockIdx.x & 7;            // channel class == XCD (round-robin)
    int q = blockIdx.x >> 3;           // [0, 24500)
    int p = q % NPAIR;                 // box-pair position, minor
    int j = q / NPAIR;                 // [0, 49) chunk within (pair, class)

    int t     = j * 256 + threadIdx.x; // [0, 12544)
    int which = t / (32 * HW);         // 0 or 1 -> box within pair
    int u     = t - which * (32 * HW);
    int cidx  = u / HW;                // [0, 32)
    int xy    = u - cidx * HW;

    int pos = 2 * p + which;
    int b   = order[pos];
    int n   = box_idx[b];
    int c   = cidx * 8 + r;

    int y = xy / CROP_W;
    int x = xy % CROP_W;

    float vy = ytab[b * CROP_H + y];
    float vx = xtab[b * CROP_H + x];

    size_t oidx = ((size_t)b * IMG_C + c) * (size_t)HW + xy;

    bool bad = (vy > (float)(IMG_H - 1)) || (vy < 0.0f) ||
               (vx > (float)(IMG_W - 1)) || (vx < 0.0f);
    if (bad) { __builtin_nontemporal_store(0.0f, &out[oidx]); return; }

    int ty = (int)floorf(vy);
    int by = (int)ceilf(vy);
    int lx = (int)floorf(vx);
    float yl = vy - (float)ty;
    float xl = vx - (float)lx;

    const float* __restrict__ plane =
        image + ((size_t)n * IMG_C + c) * (size_t)PLANE;

    // Pair {col basex, basex+1}; basex=min(lx,198) keeps it in-row. lx>basex
    // only when lx==199, where vx==199 exactly -> xl==0 and tr is irrelevant.
    int basex = min(lx, IMG_W - 2);
    const float* pt = plane + ty * IMG_W + basex;
    const float* pb = plane + by * IMG_W + basex;

    f2 vt, vb;
    asm volatile(
        "global_load_dwordx2 %0, %2, off\n\t"
        "global_load_dwordx2 %1, %3, off\n\t"
        "s_waitcnt vmcnt(0)"
        : "=&v"(vt), "=&v"(vb)
        : "v"(pt), "v"(pb));

    float tl = (lx > basex) ? vt.y : vt.x;
    float tr = vt.y;
    float bl = (lx > basex) ? vb.y : vb.x;
    float br = vb.y;

    float top = tl + xl * (tr - tl);
    float bot = bl + xl * (br - bl);
    float v   = top + yl * (bot - top);
    __builtin_nontemporal_store(v, &out[oidx]);
}

extern "C" void kernel_launch(void* const* d_in, const int* in_sizes, int n_in,
                              void* d_out, int out_size, void* d_ws, size_t ws_size,
                              hipStream_t stream) {
    const float* image   = (const float*)d_in[0];
    const float* boxes   = (const float*)d_in[1];
    const int*   box_idx = (const int*)d_in[2];
    float* out  = (float*)d_out;

    // ws: order (1000 int) @0 | ytab (1000*14 f32) @4096 | xtab after
    int*   order = (int*)d_ws;
    float* ytab  = (float*)((char*)d_ws + 4096);
    float* xtab  = ytab + N_BOXES * CROP_H;

    prep_kernel<<<1, 512, 0, stream>>>(boxes, box_idx, order, ytab, xtab);

    int grid = NPAIR * CHUNKS * 8;   // 196,000 blocks of 256 fully-active
    crop_resize_kernel<<<grid, 256, 0, stream>>>(image, box_idx, order,
                                                 ytab, xtab, out);
}

// Round 11
// 284.135 us; speedup vs baseline: 1.2800x; 1.2800x over previous
//
#include <hip/hip_runtime.h>

#define CROP_H 14
#define CROP_W 14
#define IMG_H 200
#define IMG_W 200
#define IMG_C 256
#define N_IMG 8
#define N_BOXES 1000
#define PLANE (IMG_H * IMG_W)
#define HW (CROP_H * CROP_W)               // 196
#define HALF_ELEMS (IMG_C * 7 * CROP_W)    // 25088 half-elems per box
#define BLOCKS_PER_BOX (HALF_ELEMS / 256)  // 98

// ---- Kernel A: bin boxes by n; precompute per-(box,t) coord tables.
__global__ __launch_bounds__(512) void prep_kernel(
    const float* __restrict__ boxes, const int* __restrict__ box_idx,
    int* __restrict__ order, float* __restrict__ ytab, float* __restrict__ xtab)
{
    __shared__ int counts[N_IMG];
    __shared__ int offsets[N_IMG];
    int tid  = threadIdx.x;
    int wave = tid >> 6;
    int lane = tid & 63;

    int cnt = 0;
    for (int i = lane; i < N_BOXES; i += 64) cnt += (box_idx[i] == wave) ? 1 : 0;
    for (int off = 32; off; off >>= 1) cnt += __shfl_down(cnt, off);
    if (lane == 0) counts[wave] = cnt;
    __syncthreads();
    if (tid == 0) {
        int s = 0;
        for (int i = 0; i < N_IMG; i++) { offsets[i] = s; s += counts[i]; }
    }
    __syncthreads();

    int base = offsets[wave];
    for (int i0 = 0; i0 < N_BOXES; i0 += 64) {
        int i = i0 + lane;
        bool p = (i < N_BOXES) && (box_idx[i] == wave);
        unsigned long long m = __ballot(p);
        unsigned long long below = m & ((1ull << lane) - 1ull);
        if (p) order[base + __popcll(below)] = i;
        base += __popcll(m);
    }

    // Raw coordinates (reference arithmetic order exactly; IEEE divide).
    for (int i = tid; i < N_BOXES * CROP_H; i += 512) {
        int b = i / CROP_H;
        int t = i % CROP_H;
        float y1 = boxes[b * 4 + 0];
        float x1 = boxes[b * 4 + 1];
        float y2 = boxes[b * 4 + 2];
        float x2 = boxes[b * 4 + 3];
        float h_scale = (y2 - y1) * (float)(IMG_H - 1) / (float)(CROP_H - 1);
        float w_scale = (x2 - x1) * (float)(IMG_W - 1) / (float)(CROP_W - 1);
        ytab[i] = y1 * (float)(IMG_H - 1) + (float)t * h_scale;
        xtab[i] = x1 * (float)(IMG_W - 1) + (float)t * w_scale;
    }
}

// ---- Kernel B: R4's exact schedule (channel-major/box-minor, n-grouped),
// but each thread computes the (y, y+7) output pair: shared x-address math,
// 8 independent loads in flight, half the waves. Branchless masking keeps
// all loads issued together.
__global__ __launch_bounds__(256) void crop_resize_kernel(
    const float* __restrict__ image,   // (8,256,200,200)
    const int*   __restrict__ box_idx, // (1000,)
    const int*   __restrict__ order,   // (1000,) n-grouped
    const float* __restrict__ ytab,    // (1000,14) raw in_y
    const float* __restrict__ xtab,    // (1000,14) raw in_x
    float*       __restrict__ out)     // (1000,256,14,14)
{
    int pos    = blockIdx.x % N_BOXES;          // box position, minor
    int within = blockIdx.x / N_BOXES;          // [0, 98), major
    int b      = order[pos];                    // uniform per block
    int elem   = within * 256 + threadIdx.x;    // [0, 25088)

    int x  = elem % CROP_W;
    int t  = elem / CROP_W;
    int y0 = t % 7;                              // first y; second is y0+7
    int c  = t / 7;

    float vx  = xtab[b * CROP_H + x];
    float vy0 = ytab[b * CROP_H + y0];
    float vy1 = ytab[b * CROP_H + y0 + 7];

    bool mx = (vx  > (float)(IMG_W - 1)) || (vx  < 0.0f);
    bool m0 = (vy0 > (float)(IMG_H - 1)) || (vy0 < 0.0f);
    bool m1 = (vy1 > (float)(IMG_H - 1)) || (vy1 < 0.0f);
    if (mx) vx  = 0.0f;   // reference: masked coords -> 0, output masked later
    if (m0) vy0 = 0.0f;
    if (m1) vy1 = 0.0f;

    int lx = (int)floorf(vx);
    int rx = (int)ceilf(vx);
    float xl = vx - (float)lx;

    int ty0 = (int)floorf(vy0);
    int by0 = (int)ceilf(vy0);
    float yl0 = vy0 - (float)ty0;
    int ty1 = (int)floorf(vy1);
    int by1 = (int)ceilf(vy1);
    float yl1 = vy1 - (float)ty1;

    int n = box_idx[b];
    const float* __restrict__ plane =
        image + ((size_t)n * IMG_C + c) * (size_t)PLANE;

    // 8 independent scalar taps, all in flight together.
    float tl0 = plane[ty0 * IMG_W + lx];
    float tr0 = plane[ty0 * IMG_W + rx];
    float bl0 = plane[by0 * IMG_W + lx];
    float br0 = plane[by0 * IMG_W + rx];
    float tl1 = plane[ty1 * IMG_W + lx];
    float tr1 = plane[ty1 * IMG_W + rx];
    float bl1 = plane[by1 * IMG_W + lx];
    float br1 = plane[by1 * IMG_W + rx];

    float top0 = tl0 + xl * (tr0 - tl0);
    float bot0 = bl0 + xl * (br0 - bl0);
    float v0   = top0 + yl0 * (bot0 - top0);
    float top1 = tl1 + xl * (tr1 - tl1);
    float bot1 = bl1 + xl * (br1 - bl1);
    float v1   = top1 + yl1 * (bot1 - top1);

    if (m0 | mx) v0 = 0.0f;
    if (m1 | mx) v1 = 0.0f;

    size_t obase = ((size_t)b * IMG_C + c) * (size_t)HW;
    __builtin_nontemporal_store(v0, &out[obase + (size_t)y0 * CROP_W + x]);
    __builtin_nontemporal_store(v1, &out[obase + (size_t)(y0 + 7) * CROP_W + x]);
}

extern "C" void kernel_launch(void* const* d_in, const int* in_sizes, int n_in,
                              void* d_out, int out_size, void* d_ws, size_t ws_size,
                              hipStream_t stream) {
    const float* image   = (const float*)d_in[0];
    const float* boxes   = (const float*)d_in[1];
    const int*   box_idx = (const int*)d_in[2];
    float* out  = (float*)d_out;

    // ws: order (1000 int) @0 | ytab (1000*14 f32) @4096 | xtab after
    int*   order = (int*)d_ws;
    float* ytab  = (float*)((char*)d_ws + 4096);
    float* xtab  = ytab + N_BOXES * CROP_H;

    prep_kernel<<<1, 512, 0, stream>>>(boxes, box_idx, order, ytab, xtab);

    int grid = N_BOXES * BLOCKS_PER_BOX;   // 98,000 blocks
    crop_resize_kernel<<<grid, 256, 0, stream>>>(image, box_idx, order,
                                                 ytab, xtab, out);
}

// Round 12
// 240.606 us; speedup vs baseline: 1.5115x; 1.1809x over previous
//
#include <hip/hip_runtime.h>

#define CROP_H 14
#define CROP_W 14
#define IMG_H 200
#define IMG_W 200
#define IMG_C 256
#define N_IMG 8
#define N_BOXES 1000
#define PLANE (IMG_H * IMG_W)
#define ELEMS_PER_BOX (IMG_C * CROP_H * CROP_W)   // 50176
#define BLOCKS_PER_BOX (ELEMS_PER_BOX / 256)      // 196

typedef float f2 __attribute__((ext_vector_type(2)));

// Kernel A: stable-bin the 1000 boxes by image index n (8 bins).
__global__ __launch_bounds__(512) void bin_boxes_kernel(
    const int* __restrict__ box_idx, int* __restrict__ order)
{
    __shared__ int counts[N_IMG];
    __shared__ int offsets[N_IMG];
    int tid  = threadIdx.x;
    int wave = tid >> 6;
    int lane = tid & 63;

    int cnt = 0;
    for (int i = lane; i < N_BOXES; i += 64) cnt += (box_idx[i] == wave) ? 1 : 0;
    for (int off = 32; off; off >>= 1) cnt += __shfl_down(cnt, off);
    if (lane == 0) counts[wave] = cnt;
    __syncthreads();
    if (tid == 0) {
        int s = 0;
        for (int i = 0; i < N_IMG; i++) { offsets[i] = s; s += counts[i]; }
    }
    __syncthreads();

    int base = offsets[wave];
    for (int i0 = 0; i0 < N_BOXES; i0 += 64) {
        int i = i0 + lane;
        bool p = (i < N_BOXES) && (box_idx[i] == wave);
        unsigned long long m = __ballot(p);
        unsigned long long below = m & ((1ull << lane) - 1ull);
        if (p) order[base + __popcll(below)] = i;
        base += __popcll(m);
    }
}

// Kernel B: R4's exact structure (1 thread = 1 output, inline coords,
// channel-major/box-minor n-grouped schedule), with the two horizontal tap
// pairs each loaded by ONE global_load_dwordx2 -> half the tap instructions
// and half the L1 line-visits (tl/tr hit the same lines).
__global__ __launch_bounds__(256) void crop_resize_kernel(
    const float* __restrict__ image,   // (8,256,200,200)
    const float* __restrict__ boxes,   // (1000,4)
    const int*   __restrict__ box_idx, // (1000,)
    const int*   __restrict__ order,   // (1000,) n-grouped box ids
    float*       __restrict__ out)     // (1000,256,14,14)
{
    int pos    = blockIdx.x % N_BOXES;          // box position (n-grouped)
    int within = blockIdx.x / N_BOXES;          // channel-chunk [0,196)
    int b      = order[pos];                    // uniform per block
    int elem   = within * 256 + threadIdx.x;    // [0, 50176)

    int x = elem % CROP_W;
    int t = elem / CROP_W;
    int y = t % CROP_H;
    int c = t / CROP_H;

    float y1 = boxes[b * 4 + 0];
    float x1 = boxes[b * 4 + 1];
    float y2 = boxes[b * 4 + 2];
    float x2 = boxes[b * 4 + 3];

    // Match reference arithmetic order exactly (IEEE divide, no fast-math).
    float h_scale = (y2 - y1) * (float)(IMG_H - 1) / (float)(CROP_H - 1);
    float w_scale = (x2 - x1) * (float)(IMG_W - 1) / (float)(CROP_W - 1);

    float in_y = y1 * (float)(IMG_H - 1) + (float)y * h_scale;
    float in_x = x1 * (float)(IMG_W - 1) + (float)x * w_scale;

    size_t oidx = (size_t)b * ELEMS_PER_BOX + elem;

    bool bad = (in_y > (float)(IMG_H - 1)) || (in_y < 0.0f) ||
               (in_x > (float)(IMG_W - 1)) || (in_x < 0.0f);
    if (bad) { __builtin_nontemporal_store(0.0f, &out[oidx]); return; }

    int ty = (int)floorf(in_y);
    int by = (int)ceilf(in_y);
    int lx = (int)floorf(in_x);
    float yl = in_y - (float)ty;
    float xl = in_x - (float)lx;

    int n = box_idx[b];
    const float* __restrict__ plane =
        image + ((size_t)n * IMG_C + c) * (size_t)PLANE;

    // Pair {basex, basex+1}; basex=min(lx,198) stays in-row. lx>basex only
    // when lx==199, where in_x==199.0 exactly -> xl==0, so the "tr" slot is
    // multiplied by zero and its (real, in-row) value is irrelevant.
    int basex = min(lx, IMG_W - 2);
    const float* pt = plane + ty * IMG_W + basex;
    const float* pb = plane + by * IMG_W + basex;

    f2 vt, vb;
    asm volatile("global_load_dwordx2 %0, %1, off" : "=v"(vt) : "v"(pt));
    asm volatile("global_load_dwordx2 %0, %1, off" : "=v"(vb) : "v"(pb));
    // Dataflow-tied wait: consumers below depend on the outputs of THIS asm,
    // so they cannot be scheduled before the vmcnt completes.
    asm volatile("s_waitcnt vmcnt(0)" : "+v"(vt), "+v"(vb));

    float tl = (lx > basex) ? vt.y : vt.x;
    float tr = vt.y;
    float bl = (lx > basex) ? vb.y : vb.x;
    float br = vb.y;

    float top = tl + xl * (tr - tl);
    float bot = bl + xl * (br - bl);
    float v   = top + yl * (bot - top);
    __builtin_nontemporal_store(v, &out[oidx]);
}

extern "C" void kernel_launch(void* const* d_in, const int* in_sizes, int n_in,
                              void* d_out, int out_size, void* d_ws, size_t ws_size,
                              hipStream_t stream) {
    const float* image   = (const float*)d_in[0];
    const float* boxes   = (const float*)d_in[1];
    const int*   box_idx = (const int*)d_in[2];
    float* out  = (float*)d_out;
    int* order  = (int*)d_ws;   // 1000 ints, rewritten every call

    bin_boxes_kernel<<<1, 512, 0, stream>>>(box_idx, order);

    int grid = N_BOXES * BLOCKS_PER_BOX;  // 196,000 blocks
    crop_resize_kernel<<<grid, 256, 0, stream>>>(image, boxes, box_idx, order, out);
}